// Round 1
// baseline (607.863 us; speedup 1.0000x reference)
//
#include <hip/hip_runtime.h>

#define IN_DIM 128
#define HID 64
#define NC 32

// ---- degree: deg[dst] += 1 ----
__global__ void deg_kernel(const int* __restrict__ dst, float* __restrict__ deg, int E) {
    int e = blockIdx.x * blockDim.x + threadIdx.x;
    if (e < E) atomicAdd(&deg[dst[e]], 1.0f);
}

// ---- dinv = rsqrt(deg + 1) (in place) ----
__global__ void dinv_kernel(float* __restrict__ deg, int n) {
    int i = blockIdx.x * blockDim.x + threadIdx.x;
    if (i < n) deg[i] = rsqrtf(deg[i] + 1.0f);
}

// ---- h0[n,64] = x[n,128] @ W0[128,64]; W0 in LDS, 4 rows/block ----
__global__ __launch_bounds__(256) void gemm0_kernel(const float* __restrict__ x,
                                                    const float* __restrict__ W,
                                                    float* __restrict__ h0, int n) {
    __shared__ float Ws[IN_DIM * HID];   // 32 KiB
    __shared__ float xs[4][IN_DIM];      // 2 KiB
    int tid = threadIdx.x;
    for (int i = tid; i < IN_DIM * HID; i += 256) Ws[i] = W[i];
    int r = tid >> 6, c = tid & 63;
    int row = blockIdx.x * 4 + r;
    if (row < n) {
        xs[r][c]      = x[row * IN_DIM + c];
        xs[r][c + 64] = x[row * IN_DIM + c + 64];
    }
    __syncthreads();
    if (row >= n) return;
    float acc = 0.f;
    #pragma unroll
    for (int k = 0; k < IN_DIM; ++k) acc += xs[r][k] * Ws[k * HID + c];
    h0[row * HID + c] = acc;
}

// ---- edge scatter layer 1: agg[dst] += h0[src] * dinv[src]*dinv[dst], 64 lanes/edge ----
__global__ __launch_bounds__(256) void edge0_kernel(const int* __restrict__ src,
                                                    const int* __restrict__ dst,
                                                    const float* __restrict__ dinv,
                                                    const float* __restrict__ h,
                                                    float* __restrict__ agg, int E) {
    int t = blockIdx.x * blockDim.x + threadIdx.x;
    int e = t >> 6;          // wave-uniform
    int c = t & 63;
    if (e >= E) return;
    int s = src[e], d = dst[e];
    float norm = dinv[s] * dinv[d];
    atomicAdd(&agg[d * HID + c], h[s * HID + c] * norm);
}

// ---- finalize layer 1: h = relu(agg + h0*dinv^2 + b0) * mask  (in place into agg) ----
__global__ void fin0_kernel(float* __restrict__ agg, const float* __restrict__ h0,
                            const float* __restrict__ dinv, const float* __restrict__ b0,
                            const float* __restrict__ mask, int n) {
    int i = blockIdx.x * blockDim.x + threadIdx.x;
    if (i >= n * HID) return;
    int node = i >> 6, c = i & 63;
    float dv = dinv[node];
    float v = agg[i] + h0[i] * dv * dv + b0[c];
    v = v > 0.f ? v : 0.f;
    agg[i] = v * mask[i];
}

// ---- hm[n,32]=h@W1, hl[n,32]=h@W2 fused; 4 rows/block, lanes 0-31 -> W1, 32-63 -> W2 ----
__global__ __launch_bounds__(256) void gemm1_kernel(const float* __restrict__ h,
                                                    const float* __restrict__ W1,
                                                    const float* __restrict__ W2,
                                                    float* __restrict__ hm,
                                                    float* __restrict__ hl, int n) {
    __shared__ float W1s[HID * NC];
    __shared__ float W2s[HID * NC];
    __shared__ float hs[4][HID];
    int tid = threadIdx.x;
    for (int i = tid; i < HID * NC; i += 256) { W1s[i] = W1[i]; W2s[i] = W2[i]; }
    int r = tid >> 6, c = tid & 63;
    int row = blockIdx.x * 4 + r;
    if (row < n) hs[r][c] = h[row * HID + c];
    __syncthreads();
    if (row >= n) return;
    if (c < NC) {
        float acc = 0.f;
        #pragma unroll
        for (int k = 0; k < HID; ++k) acc += hs[r][k] * W1s[k * NC + c];
        hm[row * NC + c] = acc;
    } else {
        int c2 = c - NC;
        float acc = 0.f;
        #pragma unroll
        for (int k = 0; k < HID; ++k) acc += hs[r][k] * W2s[k * NC + c2];
        hl[row * NC + c2] = acc;
    }
}

// ---- edge scatter layer 2: both heads in one pass, 64 lanes/edge (32 mu + 32 lv) ----
__global__ __launch_bounds__(256) void edge1_kernel(const int* __restrict__ src,
                                                    const int* __restrict__ dst,
                                                    const float* __restrict__ dinv,
                                                    const float* __restrict__ hm,
                                                    const float* __restrict__ hl,
                                                    float* __restrict__ mu,
                                                    float* __restrict__ lv, int E) {
    int t = blockIdx.x * blockDim.x + threadIdx.x;
    int e = t >> 6;          // wave-uniform
    int c = t & 63;
    if (e >= E) return;
    int s = src[e], d = dst[e];
    float norm = dinv[s] * dinv[d];
    if (c < NC) {
        atomicAdd(&mu[d * NC + c], hm[s * NC + c] * norm);
    } else {
        int c2 = c - NC;
        atomicAdd(&lv[d * NC + c2], hl[s * NC + c2] * norm);
    }
}

// ---- finalize layer 2 + reparameterize ----
__global__ void fin1_kernel(float* __restrict__ mu, float* __restrict__ lv,
                            const float* __restrict__ hm, const float* __restrict__ hl,
                            const float* __restrict__ dinv, const float* __restrict__ b1,
                            const float* __restrict__ b2, const float* __restrict__ eps,
                            float* __restrict__ z, int n) {
    int i = blockIdx.x * blockDim.x + threadIdx.x;
    if (i >= n * NC) return;
    int node = i >> 5, c = i & 31;
    float dv = dinv[node];
    float dv2 = dv * dv;
    float m = mu[i] + hm[i] * dv2 + b1[c];
    float l = lv[i] + hl[i] * dv2 + b2[c];
    mu[i] = m;
    lv[i] = l;
    z[i] = eps[i] * expf(l) + m;
}

extern "C" void kernel_launch(void* const* d_in, const int* in_sizes, int n_in,
                              void* d_out, int out_size, void* d_ws, size_t ws_size,
                              hipStream_t stream) {
    const float* x    = (const float*)d_in[0];
    const int*   ei   = (const int*)d_in[1];
    const float* W0   = (const float*)d_in[2];
    const float* b0   = (const float*)d_in[3];
    const float* W1   = (const float*)d_in[4];
    const float* b1   = (const float*)d_in[5];
    const float* W2   = (const float*)d_in[6];
    const float* b2   = (const float*)d_in[7];
    const float* mask = (const float*)d_in[8];
    const float* eps  = (const float*)d_in[9];

    int n = in_sizes[0] / IN_DIM;   // 50000
    int E = in_sizes[1] / 2;        // 800000
    const int* src = ei;
    const int* dst = ei + E;

    // workspace layout (floats)
    float* ws   = (float*)d_ws;
    float* dinv = ws;                         // n (deg -> dinv in place), pad to 50048
    float* h0   = ws + 50048;                 // n*64
    float* agg0 = h0 + (size_t)n * HID;       // n*64  (becomes h after fin0)
    float* hm   = agg0 + (size_t)n * HID;     // n*32
    float* hl   = hm + (size_t)n * NC;        // n*32

    float* zout  = (float*)d_out;             // n*32
    float* muout = zout + (size_t)n * NC;     // n*32
    float* lvout = muout + (size_t)n * NC;    // n*32

    hipMemsetAsync(dinv, 0, (size_t)n * sizeof(float), stream);
    hipMemsetAsync(agg0, 0, (size_t)n * HID * sizeof(float), stream);
    hipMemsetAsync(muout, 0, (size_t)2 * n * NC * sizeof(float), stream);

    deg_kernel<<<(E + 255) / 256, 256, 0, stream>>>(dst, dinv, E);
    dinv_kernel<<<(n + 255) / 256, 256, 0, stream>>>(dinv, n);
    gemm0_kernel<<<(n + 3) / 4, 256, 0, stream>>>(x, W0, h0, n);

    long t0 = (long)E * 64;
    edge0_kernel<<<(int)((t0 + 255) / 256), 256, 0, stream>>>(src, dst, dinv, h0, agg0, E);
    fin0_kernel<<<(n * HID + 255) / 256, 256, 0, stream>>>(agg0, h0, dinv, b0, mask, n);

    gemm1_kernel<<<(n + 3) / 4, 256, 0, stream>>>(agg0, W1, W2, hm, hl, n);
    edge1_kernel<<<(int)((t0 + 255) / 256), 256, 0, stream>>>(src, dst, dinv, hm, hl, muout, lvout, E);
    fin1_kernel<<<(n * NC + 255) / 256, 256, 0, stream>>>(muout, lvout, hm, hl, dinv, b1, b2, eps, zout, n);
}

// Round 4
// 400.136 us; speedup vs baseline: 1.5191x; 1.5191x over previous
//
#include <hip/hip_runtime.h>

#define IN_DIM 128
#define HID 64
#define NC 32
#define SCAN_TILE 2048   // 256 threads x 8

// ---- histogram: deg_i[dst]++ ----
__global__ void hist_kernel(const int* __restrict__ dst, int* __restrict__ deg, int E) {
    int e = blockIdx.x * blockDim.x + threadIdx.x;
    if (e < E) atomicAdd(&deg[dst[e]], 1);
}

// ---- per-tile inclusive scan (2048 ints/block) ----
__global__ __launch_bounds__(256) void scan_tile_kernel(const int* __restrict__ in,
                                                        int* __restrict__ out,
                                                        int* __restrict__ partials, int n) {
    __shared__ int tsum[256];
    int t = threadIdx.x;
    int base = blockIdx.x * SCAN_TILE + t * 8;
    int v[8];
    int s = 0;
    #pragma unroll
    for (int j = 0; j < 8; ++j) {
        int idx = base + j;
        int x = (idx < n) ? in[idx] : 0;
        s += x;
        v[j] = s;             // inclusive within thread
    }
    tsum[t] = s;
    __syncthreads();
    for (int off = 1; off < 256; off <<= 1) {
        int add = (t >= off) ? tsum[t - off] : 0;
        __syncthreads();
        tsum[t] += add;
        __syncthreads();
    }
    int excl = tsum[t] - s;   // exclusive-before-thread within tile
    #pragma unroll
    for (int j = 0; j < 8; ++j) {
        int idx = base + j;
        if (idx < n) out[idx] = v[j] + excl;
    }
    if (t == 255) partials[blockIdx.x] = tsum[255];
}

// ---- scan the tile partials (tiny, serial) ----
__global__ void scan_partials_kernel(int* __restrict__ partials, int nb) {
    if (threadIdx.x == 0 && blockIdx.x == 0) {
        int run = 0;
        for (int b = 0; b < nb; ++b) { int x = partials[b]; partials[b] = run; run += x; }
    }
}

// ---- rowptr[i+1] = tile_scan[i] + tile_offset; rowptr[0]=0 ----
__global__ void rowptr_kernel(const int* __restrict__ scan_buf, const int* __restrict__ partials,
                              int* __restrict__ rowptr, int n) {
    int i = blockIdx.x * blockDim.x + threadIdx.x;
    if (i < n) rowptr[i + 1] = scan_buf[i] + partials[i / SCAN_TILE];
    if (i == 0) rowptr[0] = 0;
}

// ---- dinv = rsqrt(deg+1) ----
__global__ void dinv_kernel(const int* __restrict__ deg, float* __restrict__ dinv, int n) {
    int i = blockIdx.x * blockDim.x + threadIdx.x;
    if (i < n) dinv[i] = rsqrtf((float)deg[i] + 1.0f);
}

// ---- scatter edges into CSR slots: e_meta[pos] = {src, norm} ----
__global__ void scatter_kernel(const int* __restrict__ src, const int* __restrict__ dst,
                               const float* __restrict__ dinv, const int* __restrict__ rowptr,
                               int* __restrict__ cursor, int2* __restrict__ e_meta, int E) {
    int e = blockIdx.x * blockDim.x + threadIdx.x;
    if (e >= E) return;
    int s = src[e], d = dst[e];
    int pos = rowptr[d] + atomicAdd(&cursor[d], 1);
    float nm = dinv[s] * dinv[d];
    e_meta[pos] = make_int2(s, __float_as_int(nm));
}

// ---- h0[n,64] = x[n,128] @ W0[128,64]; 16 rows/block, 4 cols/thread ----
__global__ __launch_bounds__(256) void gemm0_kernel(const float* __restrict__ x,
                                                    const float* __restrict__ W,
                                                    float* __restrict__ h0, int n) {
    __shared__ float Ws[IN_DIM * HID];    // 32 KiB
    __shared__ float xs[16][IN_DIM];      // 8 KiB
    int tid = threadIdx.x;
    const float4* W4 = (const float4*)W;
    float4* Ws4 = (float4*)Ws;
    #pragma unroll
    for (int j = 0; j < 8; ++j) Ws4[tid + 256 * j] = W4[tid + 256 * j];
    int base = blockIdx.x * 16;
    const float4* x4 = (const float4*)(x + (size_t)base * IN_DIM);
    float4* xs4 = (float4*)xs;
    #pragma unroll
    for (int j = 0; j < 2; ++j) {
        int i = tid + 256 * j;            // 512 float4 = 16 rows
        if (base + (i >> 5) < n) xs4[i] = x4[i];
    }
    __syncthreads();
    int r = tid >> 4;                     // 0..15
    int c4 = (tid & 15) * 4;              // 0,4,...,60
    int row = base + r;
    if (row >= n) return;
    float4 acc = make_float4(0.f, 0.f, 0.f, 0.f);
    #pragma unroll
    for (int k = 0; k < IN_DIM; ++k) {
        float xv = xs[r][k];
        float4 w = *(const float4*)&Ws[k * HID + c4];
        acc.x += xv * w.x; acc.y += xv * w.y; acc.z += xv * w.z; acc.w += xv * w.w;
    }
    *(float4*)&h0[(size_t)row * HID + c4] = acc;
}

// ---- gather layer 1 + finalize: one wave per dst node ----
__global__ __launch_bounds__(256) void gather0_kernel(const int* __restrict__ rowptr,
                                                      const int2* __restrict__ e_meta,
                                                      const float* __restrict__ h0,
                                                      const float* __restrict__ dinv,
                                                      const float* __restrict__ b0,
                                                      const float* __restrict__ mask,
                                                      float* __restrict__ h, int n) {
    int v = blockIdx.x * 4 + (threadIdx.x >> 6);
    int c = threadIdx.x & 63;
    if (v >= n) return;
    int start = rowptr[v], end = rowptr[v + 1];
    float acc = 0.f;
    for (int p = start; p < end; ++p) {
        int2 m = e_meta[p];
        acc += h0[(size_t)m.x * HID + c] * __int_as_float(m.y);
    }
    float dv = dinv[v];
    float val = acc + h0[(size_t)v * HID + c] * dv * dv + b0[c];
    val = val > 0.f ? val : 0.f;
    h[(size_t)v * HID + c] = val * mask[(size_t)v * HID + c];
}

// ---- hm=h@W1, hl=h@W2 fused; 16 rows/block ----
__global__ __launch_bounds__(256) void gemm1_kernel(const float* __restrict__ h,
                                                    const float* __restrict__ W1,
                                                    const float* __restrict__ W2,
                                                    float* __restrict__ hm,
                                                    float* __restrict__ hl, int n) {
    __shared__ float W1s[HID * NC];       // 8 KiB
    __shared__ float W2s[HID * NC];       // 8 KiB
    __shared__ float hs[16][HID];         // 4 KiB
    int tid = threadIdx.x;
    const float4* W14 = (const float4*)W1;
    const float4* W24 = (const float4*)W2;
    float4* W1s4 = (float4*)W1s;
    float4* W2s4 = (float4*)W2s;
    #pragma unroll
    for (int j = 0; j < 2; ++j) {
        W1s4[tid + 256 * j] = W14[tid + 256 * j];
        W2s4[tid + 256 * j] = W24[tid + 256 * j];
    }
    int base = blockIdx.x * 16;
    const float4* h4 = (const float4*)(h + (size_t)base * HID);
    float4* hs4 = (float4*)hs;
    if (base + (tid >> 4) < n) hs4[tid] = h4[tid];   // 256 f4 = 16 rows
    __syncthreads();
    int r = tid >> 4;
    int q = tid & 15;
    int head = q >> 3;
    int c4 = (q & 7) * 4;
    int row = base + r;
    if (row >= n) return;
    const float* Wp = head ? W2s : W1s;
    float4 acc = make_float4(0.f, 0.f, 0.f, 0.f);
    #pragma unroll
    for (int k = 0; k < HID; ++k) {
        float xv = hs[r][k];
        float4 w = *(const float4*)&Wp[k * NC + c4];
        acc.x += xv * w.x; acc.y += xv * w.y; acc.z += xv * w.z; acc.w += xv * w.w;
    }
    float* outp = head ? hl : hm;
    *(float4*)&outp[(size_t)row * NC + c4] = acc;
}

// ---- gather layer 2 + finalize + reparameterize: one wave per node ----
__global__ __launch_bounds__(256) void gather1_kernel(const int* __restrict__ rowptr,
                                                      const int2* __restrict__ e_meta,
                                                      const float* __restrict__ hm,
                                                      const float* __restrict__ hl,
                                                      const float* __restrict__ dinv,
                                                      const float* __restrict__ b1,
                                                      const float* __restrict__ b2,
                                                      const float* __restrict__ eps,
                                                      float* __restrict__ zout,
                                                      float* __restrict__ muout,
                                                      float* __restrict__ lvout, int n) {
    int v = blockIdx.x * 4 + (threadIdx.x >> 6);
    int c = threadIdx.x & 63;
    if (v >= n) return;
    int col = c & 31;
    int head = c >> 5;                    // 0 = mu, 1 = logvar
    const float* src = head ? hl : hm;
    int start = rowptr[v], end = rowptr[v + 1];
    float acc = 0.f;
    for (int p = start; p < end; ++p) {
        int2 m = e_meta[p];
        acc += src[(size_t)m.x * NC + col] * __int_as_float(m.y);
    }
    float dv = dinv[v];
    float dv2 = dv * dv;
    const float* bb = head ? b2 : b1;
    float val = acc + src[(size_t)v * NC + col] * dv2 + bb[col];
    // lanes 0-31 hold mu, lanes 32-63 hold logvar for the same col
    float other = __shfl(val, c ^ 32);    // mu lane gets logvar, lv lane gets mu
    if (head == 0) {
        muout[(size_t)v * NC + col] = val;
        zout[(size_t)v * NC + col] = eps[(size_t)v * NC + col] * expf(other) + val;
    } else {
        lvout[(size_t)v * NC + col] = val;
    }
}

extern "C" void kernel_launch(void* const* d_in, const int* in_sizes, int n_in,
                              void* d_out, int out_size, void* d_ws, size_t ws_size,
                              hipStream_t stream) {
    const float* x    = (const float*)d_in[0];
    const int*   ei   = (const int*)d_in[1];
    const float* W0   = (const float*)d_in[2];
    const float* b0   = (const float*)d_in[3];
    const float* W1   = (const float*)d_in[4];
    const float* b1   = (const float*)d_in[5];
    const float* W2   = (const float*)d_in[6];
    const float* b2   = (const float*)d_in[7];
    const float* mask = (const float*)d_in[8];
    const float* eps  = (const float*)d_in[9];

    int n = in_sizes[0] / IN_DIM;   // 50000
    int E = in_sizes[1] / 2;        // 800000
    const int* src = ei;
    const int* dst = ei + E;

    // workspace layout (4-byte units)
    int*   ws_i    = (int*)d_ws;
    int*   deg_i   = ws_i;                       // 50048
    int*   cursor  = deg_i + 50048;              // 50048 (adjacent -> one memset)
    int*   rowptr  = cursor + 50048;             // 50056
    int*   scanbuf = rowptr + 50056;             // 50048
    int*   partials= scanbuf + 50048;            // 64
    float* dinv    = (float*)(partials + 64);    // 50048
    int2*  e_meta  = (int2*)(dinv + 50048);      // E int2 = 1.6M ints
    float* h0      = (float*)(e_meta + E);       // n*64
    float* h       = h0 + (size_t)n * HID;       // n*64
    float* hm      = h + (size_t)n * HID;        // n*32
    float* hl      = hm + (size_t)n * NC;        // n*32

    float* zout  = (float*)d_out;                // n*32
    float* muout = zout + (size_t)n * NC;
    float* lvout = muout + (size_t)n * NC;

    int nb = (n + SCAN_TILE - 1) / SCAN_TILE;    // 25

    hipMemsetAsync(deg_i, 0, 2 * 50048 * sizeof(int), stream);  // deg + cursor

    hist_kernel<<<(E + 255) / 256, 256, 0, stream>>>(dst, deg_i, E);
    scan_tile_kernel<<<nb, 256, 0, stream>>>(deg_i, scanbuf, partials, n);
    scan_partials_kernel<<<1, 64, 0, stream>>>(partials, nb);
    rowptr_kernel<<<(n + 255) / 256, 256, 0, stream>>>(scanbuf, partials, rowptr, n);
    dinv_kernel<<<(n + 255) / 256, 256, 0, stream>>>(deg_i, dinv, n);
    gemm0_kernel<<<(n + 15) / 16, 256, 0, stream>>>(x, W0, h0, n);
    scatter_kernel<<<(E + 255) / 256, 256, 0, stream>>>(src, dst, dinv, rowptr, cursor, e_meta, E);
    gather0_kernel<<<(n + 3) / 4, 256, 0, stream>>>(rowptr, e_meta, h0, dinv, b0, mask, h, n);
    gemm1_kernel<<<(n + 15) / 16, 256, 0, stream>>>(h, W1, W2, hm, hl, n);
    gather1_kernel<<<(n + 3) / 4, 256, 0, stream>>>(rowptr, e_meta, hm, hl, dinv, b1, b2, eps,
                                                    zout, muout, lvout, n);
}

// Round 5
// 303.561 us; speedup vs baseline: 2.0024x; 1.3181x over previous
//
#include <hip/hip_runtime.h>

#define IN_DIM 128
#define HID 64
#define NC 32
#define SCAN_TILE 2048   // 256 threads x 8

// ---- histogram: deg_i[dst]++ ----
__global__ void hist_kernel(const int* __restrict__ dst, int* __restrict__ deg, int E) {
    int e = blockIdx.x * blockDim.x + threadIdx.x;
    if (e < E) atomicAdd(&deg[dst[e]], 1);
}

// ---- per-tile inclusive scan (2048 ints/block) ----
__global__ __launch_bounds__(256) void scan_tile_kernel(const int* __restrict__ in,
                                                        int* __restrict__ out,
                                                        int* __restrict__ partials, int n) {
    __shared__ int tsum[256];
    int t = threadIdx.x;
    int base = blockIdx.x * SCAN_TILE + t * 8;
    int v[8];
    int s = 0;
    #pragma unroll
    for (int j = 0; j < 8; ++j) {
        int idx = base + j;
        int x = (idx < n) ? in[idx] : 0;
        s += x;
        v[j] = s;             // inclusive within thread
    }
    tsum[t] = s;
    __syncthreads();
    for (int off = 1; off < 256; off <<= 1) {
        int add = (t >= off) ? tsum[t - off] : 0;
        __syncthreads();
        tsum[t] += add;
        __syncthreads();
    }
    int excl = tsum[t] - s;   // exclusive-before-thread within tile
    #pragma unroll
    for (int j = 0; j < 8; ++j) {
        int idx = base + j;
        if (idx < n) out[idx] = v[j] + excl;
    }
    if (t == 255) partials[blockIdx.x] = tsum[255];
}

// ---- scan the tile partials (tiny, serial) ----
__global__ void scan_partials_kernel(int* __restrict__ partials, int nb) {
    if (threadIdx.x == 0 && blockIdx.x == 0) {
        int run = 0;
        for (int b = 0; b < nb; ++b) { int x = partials[b]; partials[b] = run; run += x; }
    }
}

// ---- rowptr[i+1] = tile_scan[i] + tile_offset; rowptr[0]=0 ----
__global__ void rowptr_kernel(const int* __restrict__ scan_buf, const int* __restrict__ partials,
                              int* __restrict__ rowptr, int n) {
    int i = blockIdx.x * blockDim.x + threadIdx.x;
    if (i < n) rowptr[i + 1] = scan_buf[i] + partials[i / SCAN_TILE];
    if (i == 0) rowptr[0] = 0;
}

// ---- dinv = rsqrt(deg+1) ----
__global__ void dinv_kernel(const int* __restrict__ deg, float* __restrict__ dinv, int n) {
    int i = blockIdx.x * blockDim.x + threadIdx.x;
    if (i < n) dinv[i] = rsqrtf((float)deg[i] + 1.0f);
}

// ---- scatter edges into CSR slots: e_meta[pos] = {src, norm} ----
__global__ void scatter_kernel(const int* __restrict__ src, const int* __restrict__ dst,
                               const float* __restrict__ dinv, const int* __restrict__ rowptr,
                               int* __restrict__ cursor, int2* __restrict__ e_meta, int E) {
    int e = blockIdx.x * blockDim.x + threadIdx.x;
    if (e >= E) return;
    int s = src[e], d = dst[e];
    int pos = rowptr[d] + atomicAdd(&cursor[d], 1);
    float nm = dinv[s] * dinv[d];
    e_meta[pos] = make_int2(s, __float_as_int(nm));
}

// ---- h0[n,64] = x[n,128] @ W0[128,64]; 16 rows/block, 4 cols/thread ----
__global__ __launch_bounds__(256) void gemm0_kernel(const float* __restrict__ x,
                                                    const float* __restrict__ W,
                                                    float* __restrict__ h0, int n) {
    __shared__ float Ws[IN_DIM * HID];    // 32 KiB
    __shared__ float xs[16][IN_DIM];      // 8 KiB
    int tid = threadIdx.x;
    const float4* W4 = (const float4*)W;
    float4* Ws4 = (float4*)Ws;
    #pragma unroll
    for (int j = 0; j < 8; ++j) Ws4[tid + 256 * j] = W4[tid + 256 * j];
    int base = blockIdx.x * 16;
    const float4* x4 = (const float4*)(x + (size_t)base * IN_DIM);
    float4* xs4 = (float4*)xs;
    #pragma unroll
    for (int j = 0; j < 2; ++j) {
        int i = tid + 256 * j;            // 512 float4 = 16 rows
        if (base + (i >> 5) < n) xs4[i] = x4[i];
    }
    __syncthreads();
    int r = tid >> 4;                     // 0..15
    int c4 = (tid & 15) * 4;              // 0,4,...,60
    int row = base + r;
    if (row >= n) return;
    float4 acc = make_float4(0.f, 0.f, 0.f, 0.f);
    #pragma unroll
    for (int k = 0; k < IN_DIM; ++k) {
        float xv = xs[r][k];
        float4 w = *(const float4*)&Ws[k * HID + c4];
        acc.x += xv * w.x; acc.y += xv * w.y; acc.z += xv * w.z; acc.w += xv * w.w;
    }
    *(float4*)&h0[(size_t)row * HID + c4] = acc;
}

// ---- gather layer 1 + finalize: one wave per dst node, 8-deep pipelined edges ----
__global__ __launch_bounds__(256) void gather0_kernel(const int* __restrict__ rowptr,
                                                      const int2* __restrict__ e_meta,
                                                      const float* __restrict__ h0,
                                                      const float* __restrict__ dinv,
                                                      const float* __restrict__ b0,
                                                      const float* __restrict__ mask,
                                                      float* __restrict__ h, int n) {
    int v = blockIdx.x * 4 + (threadIdx.x >> 6);
    int c = threadIdx.x & 63;
    if (v >= n) return;
    int start = rowptr[v], end = rowptr[v + 1];
    float acc = 0.f;
    for (int p = start; p < end; p += 8) {
        int2 mm[8]; float ww[8];
        #pragma unroll
        for (int i = 0; i < 8; ++i) {
            int q = p + i;
            int qi = q < end ? q : end - 1;   // clamp: duplicate loads are cache-hits
            mm[i] = e_meta[qi];
            ww[i] = (q < end) ? __int_as_float(mm[i].y) : 0.f;
        }
        float gg[8];
        #pragma unroll
        for (int i = 0; i < 8; ++i) gg[i] = h0[(size_t)mm[i].x * HID + c];
        #pragma unroll
        for (int i = 0; i < 8; ++i) acc += gg[i] * ww[i];
    }
    float dv = dinv[v];
    float val = acc + h0[(size_t)v * HID + c] * dv * dv + b0[c];
    val = val > 0.f ? val : 0.f;
    h[(size_t)v * HID + c] = val * mask[(size_t)v * HID + c];
}

// ---- gather layer 2: agg2 = A_norm @ h (pure aggregation, 8-deep pipelined) ----
__global__ __launch_bounds__(256) void gather2_kernel(const int* __restrict__ rowptr,
                                                      const int2* __restrict__ e_meta,
                                                      const float* __restrict__ h,
                                                      float* __restrict__ agg2, int n) {
    int v = blockIdx.x * 4 + (threadIdx.x >> 6);
    int c = threadIdx.x & 63;
    if (v >= n) return;
    int start = rowptr[v], end = rowptr[v + 1];
    float acc = 0.f;
    for (int p = start; p < end; p += 8) {
        int2 mm[8]; float ww[8];
        #pragma unroll
        for (int i = 0; i < 8; ++i) {
            int q = p + i;
            int qi = q < end ? q : end - 1;
            mm[i] = e_meta[qi];
            ww[i] = (q < end) ? __int_as_float(mm[i].y) : 0.f;
        }
        float gg[8];
        #pragma unroll
        for (int i = 0; i < 8; ++i) gg[i] = h[(size_t)mm[i].x * HID + c];
        #pragma unroll
        for (int i = 0; i < 8; ++i) acc += gg[i] * ww[i];
    }
    agg2[(size_t)v * HID + c] = acc;
}

// ---- fused final GEMM + reparameterize:
//      S = agg2 + dinv^2*h ; mu = S@W1+b1 ; lv = S@W2+b2 ; z = eps*exp(lv)+mu ----
__global__ __launch_bounds__(256) void gemm2_kernel(const float* __restrict__ h,
                                                    const float* __restrict__ agg2,
                                                    const float* __restrict__ dinv,
                                                    const float* __restrict__ W1,
                                                    const float* __restrict__ W2,
                                                    const float* __restrict__ b1,
                                                    const float* __restrict__ b2,
                                                    const float* __restrict__ eps,
                                                    float* __restrict__ zout,
                                                    float* __restrict__ muout,
                                                    float* __restrict__ lvout, int n) {
    __shared__ float W1s[HID * NC];       // 8 KiB
    __shared__ float W2s[HID * NC];       // 8 KiB
    __shared__ float Ss[16][HID];         // 4 KiB
    int tid = threadIdx.x;
    const float4* W14 = (const float4*)W1;
    const float4* W24 = (const float4*)W2;
    float4* W1s4 = (float4*)W1s;
    float4* W2s4 = (float4*)W2s;
    #pragma unroll
    for (int j = 0; j < 2; ++j) {
        W1s4[tid + 256 * j] = W14[tid + 256 * j];
        W2s4[tid + 256 * j] = W24[tid + 256 * j];
    }
    int base = blockIdx.x * 16;
    {   // stage S: 256 threads x 1 float4 = 16 rows x 64 cols
        int row = base + (tid >> 4);
        int cc = (tid & 15) * 4;
        if (row < n) {
            float dv = dinv[row];
            float dv2 = dv * dv;
            float4 hv = *(const float4*)&h[(size_t)row * HID + cc];
            float4 av = *(const float4*)&agg2[(size_t)row * HID + cc];
            float4 s;
            s.x = av.x + dv2 * hv.x; s.y = av.y + dv2 * hv.y;
            s.z = av.z + dv2 * hv.z; s.w = av.w + dv2 * hv.w;
            *(float4*)&Ss[tid >> 4][cc] = s;
        }
    }
    __syncthreads();
    int r = tid >> 4;
    int q = tid & 15;
    int head = q >> 3;                    // 0 = mu (W1), 1 = logvar (W2)
    int c4 = (q & 7) * 4;
    int row = base + r;
    if (row >= n) return;
    const float* Wp = head ? W2s : W1s;
    float4 acc = make_float4(0.f, 0.f, 0.f, 0.f);
    #pragma unroll
    for (int k = 0; k < HID; ++k) {
        float xv = Ss[r][k];
        float4 w = *(const float4*)&Wp[k * NC + c4];
        acc.x += xv * w.x; acc.y += xv * w.y; acc.z += xv * w.z; acc.w += xv * w.w;
    }
    const float* bb = head ? b2 : b1;
    acc.x += bb[c4]; acc.y += bb[c4 + 1]; acc.z += bb[c4 + 2]; acc.w += bb[c4 + 3];
    // exchange with partner thread (same wave, lane^8): head0 holds mu, head1 holds lv
    int lane = threadIdx.x & 63;
    float4 other;
    other.x = __shfl(acc.x, lane ^ 8);
    other.y = __shfl(acc.y, lane ^ 8);
    other.z = __shfl(acc.z, lane ^ 8);
    other.w = __shfl(acc.w, lane ^ 8);
    size_t o = (size_t)row * NC + c4;
    if (head == 0) {
        *(float4*)&muout[o] = acc;
        float4 ev = *(const float4*)&eps[o];
        float4 z;
        z.x = ev.x * expf(other.x) + acc.x;
        z.y = ev.y * expf(other.y) + acc.y;
        z.z = ev.z * expf(other.z) + acc.z;
        z.w = ev.w * expf(other.w) + acc.w;
        *(float4*)&zout[o] = z;
    } else {
        *(float4*)&lvout[o] = acc;
    }
}

extern "C" void kernel_launch(void* const* d_in, const int* in_sizes, int n_in,
                              void* d_out, int out_size, void* d_ws, size_t ws_size,
                              hipStream_t stream) {
    const float* x    = (const float*)d_in[0];
    const int*   ei   = (const int*)d_in[1];
    const float* W0   = (const float*)d_in[2];
    const float* b0   = (const float*)d_in[3];
    const float* W1   = (const float*)d_in[4];
    const float* b1   = (const float*)d_in[5];
    const float* W2   = (const float*)d_in[6];
    const float* b2   = (const float*)d_in[7];
    const float* mask = (const float*)d_in[8];
    const float* eps  = (const float*)d_in[9];

    int n = in_sizes[0] / IN_DIM;   // 50000
    int E = in_sizes[1] / 2;        // 800000
    const int* src = ei;
    const int* dst = ei + E;

    // workspace layout (4-byte units)
    int*   ws_i    = (int*)d_ws;
    int*   deg_i   = ws_i;                       // 50048
    int*   cursor  = deg_i + 50048;              // 50048 (adjacent -> one memset)
    int*   rowptr  = cursor + 50048;             // 50056
    int*   scanbuf = rowptr + 50056;             // 50048
    int*   partials= scanbuf + 50048;            // 64
    float* dinv    = (float*)(partials + 64);    // 50048
    int2*  e_meta  = (int2*)(dinv + 50048);      // E int2
    float* h0      = (float*)(e_meta + E);       // n*64
    float* h       = h0 + (size_t)n * HID;       // n*64
    float* agg2    = h + (size_t)n * HID;        // n*64

    float* zout  = (float*)d_out;                // n*32
    float* muout = zout + (size_t)n * NC;
    float* lvout = muout + (size_t)n * NC;

    int nb = (n + SCAN_TILE - 1) / SCAN_TILE;    // 25

    hipMemsetAsync(deg_i, 0, 2 * 50048 * sizeof(int), stream);  // deg + cursor

    hist_kernel<<<(E + 255) / 256, 256, 0, stream>>>(dst, deg_i, E);
    scan_tile_kernel<<<nb, 256, 0, stream>>>(deg_i, scanbuf, partials, n);
    scan_partials_kernel<<<1, 64, 0, stream>>>(partials, nb);
    rowptr_kernel<<<(n + 255) / 256, 256, 0, stream>>>(scanbuf, partials, rowptr, n);
    dinv_kernel<<<(n + 255) / 256, 256, 0, stream>>>(deg_i, dinv, n);
    gemm0_kernel<<<(n + 15) / 16, 256, 0, stream>>>(x, W0, h0, n);
    scatter_kernel<<<(E + 255) / 256, 256, 0, stream>>>(src, dst, dinv, rowptr, cursor, e_meta, E);
    gather0_kernel<<<(n + 3) / 4, 256, 0, stream>>>(rowptr, e_meta, h0, dinv, b0, mask, h, n);
    gather2_kernel<<<(n + 3) / 4, 256, 0, stream>>>(rowptr, e_meta, h, agg2, n);
    gemm2_kernel<<<(n + 15) / 16, 256, 0, stream>>>(h, agg2, dinv, W1, W2, b1, b2, eps,
                                                    zout, muout, lvout, n);
}

// Round 16
// 262.948 us; speedup vs baseline: 2.3117x; 1.1545x over previous
//
#include <hip/hip_runtime.h>

#define IN_DIM 128
#define HID 64
#define NC 32
#define SCAN_TILE 2048   // 256 threads x 8

__device__ __forceinline__ unsigned short f2bf(float f) {
    unsigned b = __float_as_uint(f);
    unsigned r = (b + 0x7FFFu + ((b >> 16) & 1u)) >> 16;   // RNE
    return (unsigned short)r;
}
__device__ __forceinline__ float bf2f(unsigned short u) {
    return __uint_as_float(((unsigned)u) << 16);
}

// ---- histogram + rank: rank[e] = old count of dst ----
__global__ void hist_kernel(const int* __restrict__ dst, int* __restrict__ deg,
                            int* __restrict__ rank, int E) {
    int e = blockIdx.x * blockDim.x + threadIdx.x;
    if (e < E) rank[e] = atomicAdd(&deg[dst[e]], 1);
}

// ---- per-tile inclusive scan (2048 ints/block) ----
__global__ __launch_bounds__(256) void scan_tile_kernel(const int* __restrict__ in,
                                                        int* __restrict__ out,
                                                        int* __restrict__ partials, int n) {
    __shared__ int tsum[256];
    int t = threadIdx.x;
    int base = blockIdx.x * SCAN_TILE + t * 8;
    int v[8];
    int s = 0;
    #pragma unroll
    for (int j = 0; j < 8; ++j) {
        int idx = base + j;
        int x = (idx < n) ? in[idx] : 0;
        s += x;
        v[j] = s;
    }
    tsum[t] = s;
    __syncthreads();
    for (int off = 1; off < 256; off <<= 1) {
        int add = (t >= off) ? tsum[t - off] : 0;
        __syncthreads();
        tsum[t] += add;
        __syncthreads();
    }
    int excl = tsum[t] - s;
    #pragma unroll
    for (int j = 0; j < 8; ++j) {
        int idx = base + j;
        if (idx < n) out[idx] = v[j] + excl;
    }
    if (t == 255) partials[blockIdx.x] = tsum[255];
}

__global__ void scan_partials_kernel(int* __restrict__ partials, int nb) {
    if (threadIdx.x == 0 && blockIdx.x == 0) {
        int run = 0;
        for (int b = 0; b < nb; ++b) { int x = partials[b]; partials[b] = run; run += x; }
    }
}

__global__ void rowptr_kernel(const int* __restrict__ scan_buf, const int* __restrict__ partials,
                              int* __restrict__ rowptr, int n) {
    int i = blockIdx.x * blockDim.x + threadIdx.x;
    if (i < n) rowptr[i + 1] = scan_buf[i] + partials[i / SCAN_TILE];
    if (i == 0) rowptr[0] = 0;
}

__global__ void dinv_kernel(const int* __restrict__ deg, float* __restrict__ dinv, int n) {
    int i = blockIdx.x * blockDim.x + threadIdx.x;
    if (i < n) dinv[i] = rsqrtf((float)deg[i] + 1.0f);
}

// ---- scatter (no atomics): e_src[rowptr[d]+rank[e]] = src ----
__global__ void scatter_kernel(const int* __restrict__ src, const int* __restrict__ dst,
                               const int* __restrict__ rank, const int* __restrict__ rowptr,
                               int* __restrict__ e_src, int E) {
    int e = blockIdx.x * blockDim.x + threadIdx.x;
    if (e >= E) return;
    int d = dst[e];
    e_src[rowptr[d] + rank[e]] = src[e];
}

// ---- hp0[n,64] = (x[n,128] @ W0[128,64]) * dinv[row], stored bf16 ----
__global__ __launch_bounds__(256) void gemm0_kernel(const float* __restrict__ x,
                                                    const float* __restrict__ W,
                                                    const float* __restrict__ dinv,
                                                    unsigned short* __restrict__ hp0, int n) {
    __shared__ float Ws[IN_DIM * HID];    // 32 KiB
    __shared__ float xs[16][IN_DIM];      // 8 KiB
    int tid = threadIdx.x;
    const float4* W4 = (const float4*)W;
    float4* Ws4 = (float4*)Ws;
    #pragma unroll
    for (int j = 0; j < 8; ++j) Ws4[tid + 256 * j] = W4[tid + 256 * j];
    int base = blockIdx.x * 16;
    const float4* x4 = (const float4*)(x + (size_t)base * IN_DIM);
    float4* xs4 = (float4*)xs;
    #pragma unroll
    for (int j = 0; j < 2; ++j) {
        int i = tid + 256 * j;
        if (base + (i >> 5) < n) xs4[i] = x4[i];
    }
    __syncthreads();
    int r = tid >> 4;
    int c4 = (tid & 15) * 4;
    int row = base + r;
    if (row >= n) return;
    float4 acc = make_float4(0.f, 0.f, 0.f, 0.f);
    #pragma unroll
    for (int k = 0; k < IN_DIM; ++k) {
        float xv = xs[r][k];
        float4 w = *(const float4*)&Ws[k * HID + c4];
        acc.x += xv * w.x; acc.y += xv * w.y; acc.z += xv * w.z; acc.w += xv * w.w;
    }
    float dv = dinv[row];
    ushort4 o;
    o.x = f2bf(acc.x * dv); o.y = f2bf(acc.y * dv);
    o.z = f2bf(acc.z * dv); o.w = f2bf(acc.w * dv);
    *(ushort4*)&hp0[(size_t)row * HID + c4] = o;
}

// ---- gather layer 1: h'[v] = relu(dinv[v]*(sum hp0[src] + hp0[v]) + b0)*mask*dinv[v] ----
__global__ __launch_bounds__(256) void gather0_kernel(const int* __restrict__ rowptr,
                                                      const int* __restrict__ e_src,
                                                      const unsigned short* __restrict__ hp0,
                                                      const float* __restrict__ dinv,
                                                      const float* __restrict__ b0,
                                                      const float* __restrict__ mask,
                                                      unsigned short* __restrict__ hb, int n) {
    int v = blockIdx.x * 4 + (threadIdx.x >> 6);
    int c = threadIdx.x & 63;
    if (v >= n) return;
    int start = rowptr[v], end = rowptr[v + 1];
    float acc = 0.f;
    for (int p = start; p < end; p += 8) {
        int ss[8];
        #pragma unroll
        for (int i = 0; i < 8; ++i) {
            int q = p + i;
            ss[i] = e_src[q < end ? q : end - 1];
        }
        unsigned short gu[8];
        #pragma unroll
        for (int i = 0; i < 8; ++i) gu[i] = hp0[(size_t)ss[i] * HID + c];
        #pragma unroll
        for (int i = 0; i < 8; ++i) acc += (p + i < end) ? bf2f(gu[i]) : 0.f;
    }
    float dv = dinv[v];
    float selfv = bf2f(hp0[(size_t)v * HID + c]);
    float val = dv * (acc + selfv) + b0[c];
    val = val > 0.f ? val : 0.f;
    val = val * mask[(size_t)v * HID + c] * dv;
    hb[(size_t)v * HID + c] = f2bf(val);
}

// ---- gather layer 2: T[v] = sum h'[src] + h'[v]  (fp32 out) ----
__global__ __launch_bounds__(256) void gather2_kernel(const int* __restrict__ rowptr,
                                                      const int* __restrict__ e_src,
                                                      const unsigned short* __restrict__ hb,
                                                      float* __restrict__ T, int n) {
    int v = blockIdx.x * 4 + (threadIdx.x >> 6);
    int c = threadIdx.x & 63;
    if (v >= n) return;
    int start = rowptr[v], end = rowptr[v + 1];
    float acc = 0.f;
    for (int p = start; p < end; p += 8) {
        int ss[8];
        #pragma unroll
        for (int i = 0; i < 8; ++i) {
            int q = p + i;
            ss[i] = e_src[q < end ? q : end - 1];
        }
        unsigned short gu[8];
        #pragma unroll
        for (int i = 0; i < 8; ++i) gu[i] = hb[(size_t)ss[i] * HID + c];
        #pragma unroll
        for (int i = 0; i < 8; ++i) acc += (p + i < end) ? bf2f(gu[i]) : 0.f;
    }
    acc += bf2f(hb[(size_t)v * HID + c]);   // self-loop
    T[(size_t)v * HID + c] = acc;
}

// ---- fused final GEMM + reparameterize: S = dinv*T ; mu=S@W1+b1 ; lv=S@W2+b2 ; z=eps*exp(lv)+mu ----
__global__ __launch_bounds__(256) void gemm2_kernel(const float* __restrict__ T,
                                                    const float* __restrict__ dinv,
                                                    const float* __restrict__ W1,
                                                    const float* __restrict__ W2,
                                                    const float* __restrict__ b1,
                                                    const float* __restrict__ b2,
                                                    const float* __restrict__ eps,
                                                    float* __restrict__ zout,
                                                    float* __restrict__ muout,
                                                    float* __restrict__ lvout, int n) {
    __shared__ float W1s[HID * NC];
    __shared__ float W2s[HID * NC];
    __shared__ float Ss[16][HID];
    int tid = threadIdx.x;
    const float4* W14 = (const float4*)W1;
    const float4* W24 = (const float4*)W2;
    float4* W1s4 = (float4*)W1s;
    float4* W2s4 = (float4*)W2s;
    #pragma unroll
    for (int j = 0; j < 2; ++j) {
        W1s4[tid + 256 * j] = W14[tid + 256 * j];
        W2s4[tid + 256 * j] = W24[tid + 256 * j];
    }
    int base = blockIdx.x * 16;
    {
        int row = base + (tid >> 4);
        int cc = (tid & 15) * 4;
        if (row < n) {
            float dv = dinv[row];
            float4 tv = *(const float4*)&T[(size_t)row * HID + cc];
            float4 s;
            s.x = dv * tv.x; s.y = dv * tv.y; s.z = dv * tv.z; s.w = dv * tv.w;
            *(float4*)&Ss[tid >> 4][cc] = s;
        }
    }
    __syncthreads();
    int r = tid >> 4;
    int q = tid & 15;
    int head = q >> 3;
    int c4 = (q & 7) * 4;
    int row = base + r;
    if (row >= n) return;
    const float* Wp = head ? W2s : W1s;
    float4 acc = make_float4(0.f, 0.f, 0.f, 0.f);
    #pragma unroll
    for (int k = 0; k < HID; ++k) {
        float xv = Ss[r][k];
        float4 w = *(const float4*)&Wp[k * NC + c4];
        acc.x += xv * w.x; acc.y += xv * w.y; acc.z += xv * w.z; acc.w += xv * w.w;
    }
    const float* bb = head ? b2 : b1;
    acc.x += bb[c4]; acc.y += bb[c4 + 1]; acc.z += bb[c4 + 2]; acc.w += bb[c4 + 3];
    int lane = threadIdx.x & 63;
    float4 other;
    other.x = __shfl(acc.x, lane ^ 8);
    other.y = __shfl(acc.y, lane ^ 8);
    other.z = __shfl(acc.z, lane ^ 8);
    other.w = __shfl(acc.w, lane ^ 8);
    size_t o = (size_t)row * NC + c4;
    if (head == 0) {
        *(float4*)&muout[o] = acc;
        float4 ev = *(const float4*)&eps[o];
        float4 z;
        z.x = ev.x * expf(other.x) + acc.x;
        z.y = ev.y * expf(other.y) + acc.y;
        z.z = ev.z * expf(other.z) + acc.z;
        z.w = ev.w * expf(other.w) + acc.w;
        *(float4*)&zout[o] = z;
    } else {
        *(float4*)&lvout[o] = acc;
    }
}

extern "C" void kernel_launch(void* const* d_in, const int* in_sizes, int n_in,
                              void* d_out, int out_size, void* d_ws, size_t ws_size,
                              hipStream_t stream) {
    const float* x    = (const float*)d_in[0];
    const int*   ei   = (const int*)d_in[1];
    const float* W0   = (const float*)d_in[2];
    const float* b0   = (const float*)d_in[3];
    const float* W1   = (const float*)d_in[4];
    const float* b1   = (const float*)d_in[5];
    const float* W2   = (const float*)d_in[6];
    const float* b2   = (const float*)d_in[7];
    const float* mask = (const float*)d_in[8];
    const float* eps  = (const float*)d_in[9];

    int n = in_sizes[0] / IN_DIM;   // 50000
    int E = in_sizes[1] / 2;        // 800000
    const int* src = ei;
    const int* dst = ei + E;

    // workspace layout (4-byte units)
    int*   ws_i    = (int*)d_ws;
    int*   deg_i   = ws_i;                        // 50048
    int*   rowptr  = deg_i + 50048;               // 50056
    int*   scanbuf = rowptr + 50056;              // 50048
    int*   partials= scanbuf + 50048;             // 64
    float* dinv    = (float*)(partials + 64);     // 50048
    int*   rank    = (int*)(dinv + 50048);        // E
    int*   e_src   = rank + E;                    // E
    unsigned short* hp0 = (unsigned short*)(e_src + E);      // n*64 bf16
    unsigned short* hb  = hp0 + (size_t)n * HID;             // n*64 bf16
    float* T       = (float*)(hb + (size_t)n * HID);         // n*64 fp32

    float* zout  = (float*)d_out;                 // n*32
    float* muout = zout + (size_t)n * NC;
    float* lvout = muout + (size_t)n * NC;

    int nb = (n + SCAN_TILE - 1) / SCAN_TILE;     // 25

    hipMemsetAsync(deg_i, 0, 50048 * sizeof(int), stream);

    hist_kernel<<<(E + 255) / 256, 256, 0, stream>>>(dst, deg_i, rank, E);
    scan_tile_kernel<<<nb, 256, 0, stream>>>(deg_i, scanbuf, partials, n);
    scan_partials_kernel<<<1, 64, 0, stream>>>(partials, nb);
    rowptr_kernel<<<(n + 255) / 256, 256, 0, stream>>>(scanbuf, partials, rowptr, n);
    dinv_kernel<<<(n + 255) / 256, 256, 0, stream>>>(deg_i, dinv, n);
    gemm0_kernel<<<(n + 15) / 16, 256, 0, stream>>>(x, W0, dinv, hp0, n);
    scatter_kernel<<<(E + 255) / 256, 256, 0, stream>>>(src, dst, rank, rowptr, e_src, E);
    gather0_kernel<<<(n + 3) / 4, 256, 0, stream>>>(rowptr, e_src, hp0, dinv, b0, mask, hb, n);
    gather2_kernel<<<(n + 3) / 4, 256, 0, stream>>>(rowptr, e_src, hb, T, n);
    gemm2_kernel<<<(n + 15) / 16, 256, 0, stream>>>(T, dinv, W1, W2, b1, b2, eps,
                                                    zout, muout, lvout, n);
}